// Round 5
// baseline (245.096 us; speedup 1.0000x reference)
//
#include <hip/hip_runtime.h>
#include <math.h>

#define IN_CAP_N   1152          // floats per row
#define ROW_F2     576           // float2 per row (1152/2) = 9*64 -> uniform lane stride
#define IN_CAP_SZ  5
#define OUT_CAP_N  55
#define NBATCH     8192
#define WAVES_PER_BLOCK 4

typedef float f32x2 __attribute__((ext_vector_type(2)));

// One WAVE per batch element. Uniform f32x2 lane-strided loads (no exec-mask
// toggling in the load stream), all loads+FMAs before any cross-lane op,
// joint 5-way butterfly reduce, then routing with the iter-1 softmax
// collapsed to a single reduction (all 5 columns of b_ij start identical).
__global__ __launch_bounds__(256) void digitcaps_fused(
    const float* __restrict__ u,      // (B, 5, 1152)
    const float* __restrict__ W,      // (1152,)
    const float* __restrict__ bparam, // (55,)
    float* __restrict__ out)          // (B, 55)
{
    const int lane = threadIdx.x & 63;
    const int wave = threadIdx.x >> 6;
    const int b    = blockIdx.x * WAVES_PER_BLOCK + wave;   // 0..8191

    // ---- preload W: 9 uniform f32x2 fragments per lane -------------------
    const f32x2* W2 = (const f32x2*)W;
    f32x2 wreg[9];
    #pragma unroll
    for (int p = 0; p < 9; ++p) wreg[p] = W2[p * 64 + lane];

    // ---- all 45 loads, then all FMAs, then one joint reduction -----------
    const f32x2* u2 = (const f32x2*)(u + (size_t)b * (IN_CAP_SZ * IN_CAP_N));
    f32x2 uv[IN_CAP_SZ][9];
    #pragma unroll
    for (int i = 0; i < IN_CAP_SZ; ++i) {
        const f32x2* row = u2 + i * ROW_F2;
        #pragma unroll
        for (int p = 0; p < 9; ++p)
            uv[i][p] = __builtin_nontemporal_load(&row[p * 64 + lane]);
    }

    float h[IN_CAP_SZ];
    #pragma unroll
    for (int i = 0; i < IN_CAP_SZ; ++i) {
        float a0 = 0.f, a1 = 0.f;
        #pragma unroll
        for (int p = 0; p < 9; ++p) {
            a0 += uv[i][p].x * wreg[p].x;
            a1 += uv[i][p].y * wreg[p].y;
        }
        h[i] = a0 + a1;
    }
    // joint butterfly: 5 independent adds per step (ILP hides ds latency)
    #pragma unroll
    for (int off = 32; off > 0; off >>= 1) {
        #pragma unroll
        for (int i = 0; i < IN_CAP_SZ; ++i)
            h[i] += __shfl_xor(h[i], off, 64);
    }

    // ---- routing: lane j in [0,55) owns out-capsule j --------------------
    const bool active = (lane < OUT_CAP_N);
    const float b0 = active ? bparam[lane] : -INFINITY;

    // iter 1: b_ij columns are identical (broadcast of b over i) -> ONE softmax
    float m = b0;
    #pragma unroll
    for (int off = 32; off > 0; off >>= 1)
        m = fmaxf(m, __shfl_xor(m, off, 64));
    float e = active ? __expf(b0 - m) : 0.f;
    float sum = e;
    #pragma unroll
    for (int off = 32; off > 0; off >>= 1)
        sum += __shfl_xor(sum, off, 64);
    const float c1 = e / sum;                      // same coupling for all i
    const float hs = h[0] + h[1] + h[2] + h[3] + h[4];
    float s = c1 * hs;
    float v = fabsf(s) * s / (1.f + s * s);        // squash, OUT_CAP_SZ==1

    // iter 2: b2[i] = b0 + v*h[i]  (differs per i) -> 5 softmaxes, ILP'd
    float x[IN_CAP_SZ], mm[IN_CAP_SZ], ee[IN_CAP_SZ], ss[IN_CAP_SZ];
    #pragma unroll
    for (int i = 0; i < IN_CAP_SZ; ++i) { x[i] = b0 + v * h[i]; mm[i] = x[i]; }
    #pragma unroll
    for (int off = 32; off > 0; off >>= 1) {
        #pragma unroll
        for (int i = 0; i < IN_CAP_SZ; ++i)
            mm[i] = fmaxf(mm[i], __shfl_xor(mm[i], off, 64));
    }
    #pragma unroll
    for (int i = 0; i < IN_CAP_SZ; ++i)
        ee[i] = active ? __expf(x[i] - mm[i]) : 0.f;
    #pragma unroll
    for (int i = 0; i < IN_CAP_SZ; ++i) ss[i] = ee[i];
    #pragma unroll
    for (int off = 32; off > 0; off >>= 1) {
        #pragma unroll
        for (int i = 0; i < IN_CAP_SZ; ++i)
            ss[i] += __shfl_xor(ss[i], off, 64);
    }
    s = 0.f;
    #pragma unroll
    for (int i = 0; i < IN_CAP_SZ; ++i) s += (ee[i] / ss[i]) * h[i];
    v = fabsf(s) * s / (1.f + s * s);              // final squash; no b update needed

    if (active)
        __builtin_nontemporal_store(v, &out[(size_t)b * OUT_CAP_N + lane]);
}

extern "C" void kernel_launch(void* const* d_in, const int* in_sizes, int n_in,
                              void* d_out, int out_size, void* d_ws, size_t ws_size,
                              hipStream_t stream) {
    const float* u  = (const float*)d_in[0];
    const float* W  = (const float*)d_in[1];
    const float* bp = (const float*)d_in[2];
    float* out = (float*)d_out;
    digitcaps_fused<<<NBATCH / WAVES_PER_BLOCK, WAVES_PER_BLOCK * 64, 0, stream>>>(u, W, bp, out);
}

// Round 6
// 242.178 us; speedup vs baseline: 1.0120x; 1.0120x over previous
//
#include <hip/hip_runtime.h>
#include <math.h>

#define IN_CAP_SZ  5
#define OUT_CAP_N  55
#define NBATCH     8192
#define ROW_F4     288            // f32x4 per 1152-float row
#define PAIR_F4    2880           // 2 batches * 5 rows * 288 = 45 * 64
#define WAVES_PER_BLOCK 4

typedef float f32x4 __attribute__((ext_vector_type(4)));

// One WAVE per PAIR of batches: 2880 f32x4 = 45 perfectly uniform, unmasked,
// contiguous dwordx4 fragments (copy-shaped load stream). W fragment for
// position (64p+lane) mod 288 has period 9 in p -> 9 preloaded f32x4/lane;
// the only lane-split (p % 9 == 4) coincides exactly with row boundaries.
__global__ __launch_bounds__(256) void digitcaps_fused(
    const float* __restrict__ u,      // (B, 5, 1152)
    const float* __restrict__ W,      // (1152,)
    const float* __restrict__ bparam, // (55,)
    float* __restrict__ out)          // (B, 55)
{
    const int lane  = threadIdx.x & 63;
    const int wave  = threadIdx.x >> 6;
    const int bpair = blockIdx.x * WAVES_PER_BLOCK + wave;   // 0..4095
    const int bA    = bpair * 2;

    // ---- W: 9 per-lane f32x4 fragments, period-9 pattern -----------------
    const f32x4* W4 = (const f32x4*)W;
    f32x4 wreg[9];
    wreg[0] = W4[lane];
    wreg[1] = W4[64 + lane];
    wreg[2] = W4[128 + lane];
    wreg[3] = W4[192 + lane];
    wreg[4] = (lane < 32) ? W4[256 + lane] : W4[lane - 32];  // wraps at lane 32
    wreg[5] = W4[32 + lane];
    wreg[6] = W4[96 + lane];
    wreg[7] = W4[160 + lane];
    wreg[8] = W4[224 + lane];

    // ---- 45 uniform nt dwordx4 loads, dot into per-row accumulators ------
    const f32x4* u4 = (const f32x4*)u + (size_t)bpair * PAIR_F4;
    float acc[2 * IN_CAP_SZ];
    #pragma unroll
    for (int r = 0; r < 10; ++r) acc[r] = 0.f;

    #pragma unroll
    for (int p = 0; p < 45; ++p) {
        f32x4 v4 = __builtin_nontemporal_load(&u4[p * 64 + lane]);
        f32x4 w4 = wreg[p % 9];
        float g = v4.x * w4.x + v4.y * w4.y + v4.z * w4.z + v4.w * w4.w;
        const int r0 = (p * 64) / ROW_F4;        // row of lane 0
        const int r1 = (p * 64 + 63) / ROW_F4;   // row of lane 63
        if (r0 == r1) {
            acc[r0] += g;
        } else {                                  // p % 9 == 4: split at lane 32
            if (lane < 32) acc[r0] += g; else acc[r1] += g;
        }
    }

    // ---- joint butterfly reduce: 10 independent streams ------------------
    #pragma unroll
    for (int off = 32; off > 0; off >>= 1) {
        #pragma unroll
        for (int r = 0; r < 10; ++r)
            acc[r] += __shfl_xor(acc[r], off, 64);
    }

    // ---- routing, lane j owns out-capsule j; batches A,B share iter-1 softmax
    const bool active = (lane < OUT_CAP_N);
    const float b0 = active ? bparam[lane] : -INFINITY;
    float m = b0;
    #pragma unroll
    for (int off = 32; off > 0; off >>= 1)
        m = fmaxf(m, __shfl_xor(m, off, 64));
    float e = active ? __expf(b0 - m) : 0.f;
    float sum = e;
    #pragma unroll
    for (int off = 32; off > 0; off >>= 1)
        sum += __shfl_xor(sum, off, 64);
    const float c1 = e / sum;                     // iter-1 coupling, all i equal

    float vout[2];
    #pragma unroll
    for (int t = 0; t < 2; ++t) {
        const float* h = acc + IN_CAP_SZ * t;
        const float hs = h[0] + h[1] + h[2] + h[3] + h[4];
        float s = c1 * hs;
        float v = fabsf(s) * s / (1.f + s * s);   // squash (OUT_CAP_SZ==1)

        // iter 2: b2[i] = b0 + v*h[i] -> 5 softmaxes, ILP'd
        float x[IN_CAP_SZ], mm[IN_CAP_SZ], ee[IN_CAP_SZ], ss[IN_CAP_SZ];
        #pragma unroll
        for (int i = 0; i < IN_CAP_SZ; ++i) { x[i] = b0 + v * h[i]; mm[i] = x[i]; }
        #pragma unroll
        for (int off = 32; off > 0; off >>= 1) {
            #pragma unroll
            for (int i = 0; i < IN_CAP_SZ; ++i)
                mm[i] = fmaxf(mm[i], __shfl_xor(mm[i], off, 64));
        }
        #pragma unroll
        for (int i = 0; i < IN_CAP_SZ; ++i)
            ee[i] = active ? __expf(x[i] - mm[i]) : 0.f;
        #pragma unroll
        for (int i = 0; i < IN_CAP_SZ; ++i) ss[i] = ee[i];
        #pragma unroll
        for (int off = 32; off > 0; off >>= 1) {
            #pragma unroll
            for (int i = 0; i < IN_CAP_SZ; ++i)
                ss[i] += __shfl_xor(ss[i], off, 64);
        }
        s = 0.f;
        #pragma unroll
        for (int i = 0; i < IN_CAP_SZ; ++i) s += (ee[i] / ss[i]) * h[i];
        vout[t] = fabsf(s) * s / (1.f + s * s);   // final squash
    }

    if (active) {
        __builtin_nontemporal_store(vout[0], &out[(size_t)bA * OUT_CAP_N + lane]);
        __builtin_nontemporal_store(vout[1], &out[(size_t)(bA + 1) * OUT_CAP_N + lane]);
    }
}

extern "C" void kernel_launch(void* const* d_in, const int* in_sizes, int n_in,
                              void* d_out, int out_size, void* d_ws, size_t ws_size,
                              hipStream_t stream) {
    const float* u  = (const float*)d_in[0];
    const float* W  = (const float*)d_in[1];
    const float* bp = (const float*)d_in[2];
    float* out = (float*)d_out;
    digitcaps_fused<<<NBATCH / 2 / WAVES_PER_BLOCK, WAVES_PER_BLOCK * 64, 0, stream>>>(u, W, bp, out);
}